// Round 21
// baseline (222.447 us; speedup 1.0000x reference)
//
#include <hip/hip_runtime.h>
#include <stdint.h>
#include <type_traits>

typedef __attribute__((ext_vector_type(8))) short short8;
typedef __attribute__((ext_vector_type(4))) short s16x4;
typedef __attribute__((ext_vector_type(4))) float f32x4;

#define S_LEN 4096
#define D_DIM 256
#define BATCH 4

__device__ __forceinline__ f32x4 mfma16(short8 a, short8 b, f32x4 c) {
    return __builtin_amdgcn_mfma_f32_16x16x32_bf16(a, b, c, 0, 0, 0);
}

// fp32 -> bf16 bits, round-to-nearest-even (matches numpy/ml_dtypes)
__device__ __forceinline__ short f2bf(float x) {
    uint32_t u = __float_as_uint(x);
    uint32_t r = (u + 0x7FFFu + ((u >> 16) & 1u)) >> 16;
    return (short)r;
}
__device__ __forceinline__ float bf2f(short s) {
    uint32_t u = ((uint32_t)(uint16_t)s) << 16;
    return __uint_as_float(u);
}

// async global->LDS, 16B per lane. LDS dest wave-uniform base; HW adds lane*16.
__device__ __forceinline__ void gload16(const short* g, short* l) {
    __builtin_amdgcn_global_load_lds(
        (const __attribute__((address_space(1))) void*)g,
        (__attribute__((address_space(3))) void*)l, 16, 0, 0);
}

// ---- x fp32 -> bf16 ----
__global__ __launch_bounds__(256) void xbf_conv(
    const float* __restrict__ x, short* __restrict__ xb)
{
    int i = blockIdx.x * 256 + threadIdx.x;   // 8 elems per thread
    f32x4 a = *reinterpret_cast<const f32x4*>(x + (size_t)i * 8);
    f32x4 b = *reinterpret_cast<const f32x4*>(x + (size_t)i * 8 + 4);
    short8 r;
#pragma unroll
    for (int k = 0; k < 4; ++k) r[k] = f2bf(a[k]);
#pragma unroll
    for (int k = 0; k < 4; ++k) r[k + 4] = f2bf(b[k]);
    *reinterpret_cast<short8*>(xb + (size_t)i * 8) = r;
}

// ---- transpose four 256x256 fp32 weights into bf16 ws (WT[z][f][d] = W[z][d][f]) ----
__global__ __launch_bounds__(256) void transpose_w(
    const float* __restrict__ wq, const float* __restrict__ wk,
    const float* __restrict__ wv, const float* __restrict__ wo,
    short* __restrict__ out)
{
    __shared__ float t[16][17];
    const float* in = blockIdx.z == 0 ? wq : blockIdx.z == 1 ? wk
                    : blockIdx.z == 2 ? wv : wo;
    short* o = out + (size_t)blockIdx.z * 65536;
    const int x0 = blockIdx.x * 16, y0 = blockIdx.y * 16;
    const int tx = threadIdx.x, ty = threadIdx.y;
    t[ty][tx] = in[(y0 + ty) * 256 + x0 + tx];
    __syncthreads();
    o[(size_t)(x0 + ty) * 256 + y0 + tx] = f2bf(t[tx][ty]);
}

// ---- fused QKV GEMM (r17-exact): [16384x768] = xb * WT^T + bias ----
__global__ __launch_bounds__(256) void gemm_qkv(
    const short* __restrict__ A, const short* __restrict__ Bt,
    const float* __restrict__ bq, const float* __restrict__ bk,
    const float* __restrict__ bv,
    short* __restrict__ QF, short* __restrict__ KF, short* __restrict__ VF)
{
    __shared__ short As[128 * 64];
    __shared__ short Bs[128 * 64];
    const int tid = threadIdx.x;
    const int lane = tid & 63;
    const int w = tid >> 6;
    const int wr = w >> 1, wc = w & 1;
    const int lo = lane & 15, hi = lane >> 4;
    const size_t m0 = (size_t)blockIdx.y * 128, n0 = (size_t)blockIdx.x * 128;
    const int reg = (int)(n0 >> 8);                  // 0=Q 1=K 2=V (block-uniform)
    const float* bias = reg == 0 ? bq : (reg == 1 ? bk : bv);

    f32x4 acc[4][4] = {};

    for (int kt = 0; kt < 4; ++kt) {
#pragma unroll
        for (int i = 0; i < 4; ++i) {
            int c = i * 4 + w;                     // chunk 0..15
            int s = c * 64 + lane;                 // 16B slot 0..1023
            int row = s >> 3, ke = (s & 7) * 8;
            gload16(A  + (m0 + row) * 256 + kt * 64 + ke, As + c * 512);
            gload16(Bt + (n0 + row) * 256 + kt * 64 + ke, Bs + c * 512);
        }
        __syncthreads();
#pragma unroll
        for (int kk = 0; kk < 2; ++kk) {
            short8 af[4], bf[4];
#pragma unroll
            for (int m = 0; m < 4; ++m)
                af[m] = *reinterpret_cast<const short8*>(&As[(wr * 64 + m * 16 + lo) * 64 + kk * 32 + hi * 8]);
#pragma unroll
            for (int n = 0; n < 4; ++n)
                bf[n] = *reinterpret_cast<const short8*>(&Bs[(wc * 64 + n * 16 + lo) * 64 + kk * 32 + hi * 8]);
#pragma unroll
            for (int m = 0; m < 4; ++m)
#pragma unroll
                for (int n = 0; n < 4; ++n)
                    acc[m][n] = mfma16(af[m], bf[n], acc[m][n]);
        }
        __syncthreads();
    }

#pragma unroll
    for (int m = 0; m < 4; ++m) {
#pragma unroll
        for (int n = 0; n < 4; ++n) {
#pragma unroll
            for (int j = 0; j < 4; ++j) {
                size_t row = m0 + wr * 64 + m * 16 + hi * 4 + j;
                int f = (int)((n0 + wc * 64 + n * 16 + lo) & 255);
                float v = acc[m][n][j] + bias[f];
                int b = (int)(row >> 12), R = (int)(row & 4095);
                if (reg == 0) {
                    int jt = R >> 4, lk = R & 15;
                    int kk = f >> 5, q = f & 31, hk = q >> 3, e = q & 7;
                    QF[((((size_t)(b * 256 + jt) * 8 + kk) * 64) + hk * 16 + lk) * 8 + e] = f2bf(v);
                } else if (reg == 1) {
                    int ktile = R >> 6, nn = (R >> 4) & 3, lk = R & 15;
                    int kk = f >> 5, q = f & 31, hk = q >> 3, e = q & 7;
                    KF[(((((size_t)(b * 64 + ktile) * 8 + kk) * 4 + nn) * 64) + hk * 16 + lk) * 8 + e] = f2bf(v);
                } else {
                    int ktile = R >> 6, t6 = R & 63, k2 = t6 >> 5, r5 = t6 & 31;
                    int hk = r5 >> 3, e = r5 & 7;
                    int nf = f >> 4, lk = f & 15;
                    VF[(((((size_t)(b * 64 + ktile) * 2 + k2) * 16 + nf) * 64) + hk * 16 + lk) * 8 + e] = f2bf(v);
                }
            }
        }
    }
}

// ---- out-proj GEMM (plain): C = S*WoT^T + bias (DIRECT fallback path) ----
__global__ __launch_bounds__(256) void gemm_out(
    const short* __restrict__ A, const short* __restrict__ Bt,
    const float* __restrict__ bias, float* __restrict__ C, int ldc)
{
    __shared__ short As[128 * 64];
    __shared__ short Bs[128 * 64];
    const int tid = threadIdx.x;
    const int lane = tid & 63;
    const int w = tid >> 6;
    const int wr = w >> 1, wc = w & 1;
    const int lo = lane & 15, hi = lane >> 4;
    const size_t m0 = (size_t)blockIdx.y * 128, n0 = (size_t)blockIdx.x * 128;

    f32x4 acc[4][4] = {};

    for (int kt = 0; kt < 4; ++kt) {
#pragma unroll
        for (int i = 0; i < 4; ++i) {
            int c = i * 4 + w;
            int s = c * 64 + lane;
            int row = s >> 3, ke = (s & 7) * 8;
            gload16(A  + (m0 + row) * 256 + kt * 64 + ke, As + c * 512);
            gload16(Bt + (n0 + row) * 256 + kt * 64 + ke, Bs + c * 512);
        }
        __syncthreads();
#pragma unroll
        for (int kk = 0; kk < 2; ++kk) {
            short8 af[4], bf[4];
#pragma unroll
            for (int m = 0; m < 4; ++m)
                af[m] = *reinterpret_cast<const short8*>(&As[(wr * 64 + m * 16 + lo) * 64 + kk * 32 + hi * 8]);
#pragma unroll
            for (int n = 0; n < 4; ++n)
                bf[n] = *reinterpret_cast<const short8*>(&Bs[(wc * 64 + n * 16 + lo) * 64 + kk * 32 + hi * 8]);
#pragma unroll
            for (int m = 0; m < 4; ++m)
#pragma unroll
                for (int n = 0; n < 4; ++n)
                    acc[m][n] = mfma16(af[m], bf[n], acc[m][n]);
        }
        __syncthreads();
    }

#pragma unroll
    for (int m = 0; m < 4; ++m)
#pragma unroll
        for (int n = 0; n < 4; ++n)
#pragma unroll
            for (int j = 0; j < 4; ++j) {
                size_t row = m0 + wr * 64 + m * 16 + hi * 4 + j;
                size_t col = n0 + wc * 64 + n * 16 + lo;
                C[row * (size_t)ldc + col] = acc[m][n][j] + bias[col];
            }
}

// ---- PML (m,l) -> in-place per-row scale factors e_p/L ----
template <int NSPLIT, int ROWS>
__global__ void calc_sfac(float* __restrict__ PML)
{
    const int bid = (int)blockIdx.x;
    const int lr = threadIdx.x;
    const size_t base = (size_t)bid * NSPLIT;

    float mm[NSPLIT], ll[NSPLIT];
    float M = -3.3e38f;
#pragma unroll
    for (int p = 0; p < NSPLIT; ++p) {
        mm[p] = PML[(base + p) * (2 * ROWS) + lr];
        ll[p] = PML[(base + p) * (2 * ROWS) + ROWS + lr];
        M = fmaxf(M, mm[p]);
    }
    float L = 0.f, e[NSPLIT];
#pragma unroll
    for (int p = 0; p < NSPLIT; ++p) { e[p] = __expf(mm[p] - M); L += ll[p] * e[p]; }
    const float inv = 1.0f / L;
#pragma unroll
    for (int p = 0; p < NSPLIT; ++p)
        PML[(base + p) * (2 * ROWS) + lr] = e[p] * inv;
}

// ---- fused merge + out-proj (r17 structure): out = (Σ_p sf_p ⊙ PO_p)*WoT^T + b ----
template <int NSPLIT, int ROWS, int JBLK>
__global__ __launch_bounds__(256) void gemm_out_fused(
    const short* __restrict__ PO, const float* __restrict__ PML,
    const short* __restrict__ Bt, const float* __restrict__ bias,
    float* __restrict__ C)
{
    __shared__ short As[128 * 64];
    __shared__ short Bs[128 * 64];
    const int tid = threadIdx.x;
    const int lane = tid & 63;
    const int w = tid >> 6;
    const int wr = w >> 1, wc = w & 1;
    const int lo = lane & 15, hi = lane >> 4;
    const size_t m0 = (size_t)blockIdx.y * 128, n0 = (size_t)blockIdx.x * 128;

    f32x4 acc[4][4] = {};

    for (int kt = 0; kt < 4; ++kt) {
        short8 va[4];
#pragma unroll
        for (int i = 0; i < 4; ++i) {
            int c = i * 4 + w;                     // chunk 0..15
            int s = c * 64 + lane;                 // 16B slot 0..1023
            int row = s >> 3, ke = (s & 7) * 8;
            size_t grow = m0 + row;
            int b = (int)(grow >> 12), R = (int)(grow & 4095);
            int jq = R / ROWS, lr = R % ROWS;
            size_t pb0 = (size_t)(b * JBLK + jq) * NSPLIT;

            float a8[8] = {};
#pragma unroll
            for (int p = 0; p < NSPLIT; ++p) {
                float sf = PML[(pb0 + p) * (2 * ROWS) + lr];
                short8 v = *reinterpret_cast<const short8*>(
                    &PO[(pb0 + p) * ((size_t)ROWS * 256) + (size_t)lr * 256 + kt * 64 + ke]);
#pragma unroll
                for (int ii = 0; ii < 8; ++ii) a8[ii] += bf2f(v[ii]) * sf;
            }
#pragma unroll
            for (int ii = 0; ii < 8; ++ii) va[i][ii] = f2bf(a8[ii]);

            gload16(Bt + (n0 + row) * 256 + kt * 64 + ke, Bs + c * 512);
        }
#pragma unroll
        for (int i = 0; i < 4; ++i) {
            int c = i * 4 + w;
            *reinterpret_cast<short8*>(&As[(c * 64 + lane) * 8]) = va[i];
        }
        __syncthreads();
#pragma unroll
        for (int kk = 0; kk < 2; ++kk) {
            short8 af[4], bf[4];
#pragma unroll
            for (int m = 0; m < 4; ++m)
                af[m] = *reinterpret_cast<const short8*>(&As[(wr * 64 + m * 16 + lo) * 64 + kk * 32 + hi * 8]);
#pragma unroll
            for (int n = 0; n < 4; ++n)
                bf[n] = *reinterpret_cast<const short8*>(&Bs[(wc * 64 + n * 16 + lo) * 64 + kk * 32 + hi * 8]);
#pragma unroll
            for (int m = 0; m < 4; ++m)
#pragma unroll
                for (int n = 0; n < 4; ++n)
                    acc[m][n] = mfma16(af[m], bf[n], acc[m][n]);
        }
        __syncthreads();
    }

#pragma unroll
    for (int m = 0; m < 4; ++m)
#pragma unroll
        for (int n = 0; n < 4; ++n)
#pragma unroll
            for (int j = 0; j < 4; ++j) {
                size_t row = m0 + wr * 64 + m * 16 + hi * 4 + j;
                size_t col = n0 + wc * 64 + n * 16 + lo;
                C[row * (size_t)256 + col] = acc[m][n][j] + bias[col];
            }
}

// ---- attn, 1024-thread blocks: 16 waves = 4 waves/SIMD guaranteed ----
// amdgpu_waves_per_eu(4,4) pins the backend to exactly 4 waves/EU -> 128-VGPR
// budget (state needs ~112). r19/r20: __launch_bounds__ 2nd arg was folded to
// waves-per-eu=8 -> 64 VGPR -> spill; this attribute is the direct control.
template <int NSPLIT>
__global__ __launch_bounds__(1024)
__attribute__((amdgpu_waves_per_eu(4, 4))) void attn_big(
    const short* __restrict__ Qf, const short* __restrict__ Kf,
    const short* __restrict__ Vf, short* __restrict__ PO,
    float* __restrict__ PML)
{
    __shared__ short Ks[2][64 * 256];   // 2 x 32 KB
    __shared__ short Vs[64 * 256];      // 32 KB (single-buffered)
    __shared__ short P[16][16 * 64];    // 32 KB, XOR-swizzled

    const int tid = threadIdx.x;
    const int lane = tid & 63;
    const int w = tid >> 6;             // wave 0..15
    const int lo = lane & 15, hi = lane >> 4;
    const int bx = (int)blockIdx.x;
    const int m = bx / (BATCH * NSPLIT);        // pair id 0..7
    const int r = bx % (BATCH * NSPLIT);
    const int b = r % BATCH;                    // bx%8 -> batch pinned to XCD pair
    const int p = r / BATCH;

    auto stageK = [&](int buf, int kt) {
        const short* Kt = Kf + (size_t)(b * 64 + kt) * 16384;
#pragma unroll
        for (int c4 = 0; c4 < 2; ++c4) {
            int c = c4 * 16 + w;                // 1KB chunk, 32 chunks over 16 waves
            gload16(Kt + c * 512 + lane * 8, &Ks[buf][c * 512]);
        }
    };
    auto stageV = [&](int kt) {
        const short* Vt = Vf + (size_t)(b * 64 + kt) * 16384;
#pragma unroll
        for (int c4 = 0; c4 < 2; ++c4) {
            int c = c4 * 16 + w;
            gload16(Vt + c * 512 + lane * 8, &Vs[c * 512]);
        }
    };

    for (int half = 0; half < 2; ++half) {
        const int j = half == 0 ? (15 - m) : m;   // 256-row q-block, long first
        const int q0 = j * 256;
        const int last = 4 * j + 3;               // last 64-key k-tile index

        short8 qv[8];
#pragma unroll
        for (int kk = 0; kk < 8; ++kk)
            qv[kk] = *reinterpret_cast<const short8*>(
                Qf + (((size_t)(b * 256 + j * 16 + w) * 8 + kk) * 64 + lane) * 8);

        f32x4 o[16] = {};
        float mrow[4] = {-1e30f, -1e30f, -1e30f, -1e30f};
        float lrow[4] = {0.f, 0.f, 0.f, 0.f};

        int cur = 0;
        if (p <= last) stageK(0, p);
        __syncthreads();                          // first K tile staged

        for (int kt = p; kt <= last; kt += NSPLIT) {
            stageV(kt);                                          // V for THIS tile
            if (kt + NSPLIT <= last) stageK(cur ^ 1, kt + NSPLIT);  // next K

            f32x4 s4[4] = {};
            __builtin_amdgcn_s_setprio(1);
#pragma unroll
            for (int kk = 0; kk < 8; ++kk) {
#pragma unroll
                for (int n = 0; n < 4; ++n) {
                    short8 kf = *reinterpret_cast<const short8*>(&Ks[cur][((kk * 4 + n) * 64 + lane) * 8]);
                    s4[n] = mfma16(qv[kk], kf, s4[n]);
                }
            }
            __builtin_amdgcn_s_setprio(0);

            const bool diag = (kt >= 4 * j);
            float pm[4] = {-1e30f, -1e30f, -1e30f, -1e30f};
#pragma unroll
            for (int n = 0; n < 4; ++n) {
#pragma unroll
                for (int jj = 0; jj < 4; ++jj) {
                    float v = s4[n][jj] * 0.0625f;  // 1/sqrt(256)
                    if (diag) {
                        int rl = q0 + w * 16 + hi * 4 + jj;
                        int cl = kt * 64 + n * 16 + lo;
                        if (cl > rl) v = -1e30f;    // causal mask
                    }
                    s4[n][jj] = v;
                    pm[jj] = fmaxf(pm[jj], v);
                }
            }
#pragma unroll
            for (int off = 1; off < 16; off <<= 1)
#pragma unroll
                for (int jj = 0; jj < 4; ++jj)
                    pm[jj] = fmaxf(pm[jj], __shfl_xor(pm[jj], off));

            float sc[4], lsum[4];
#pragma unroll
            for (int jj = 0; jj < 4; ++jj) {
                float mn = fmaxf(mrow[jj], pm[jj]);
                sc[jj] = __expf(mrow[jj] - mn);
                mrow[jj] = mn;
                lsum[jj] = 0.f;
            }
#pragma unroll
            for (int n = 0; n < 4; ++n)
#pragma unroll
                for (int jj = 0; jj < 4; ++jj) {
                    float pv = __expf(s4[n][jj] - mrow[jj]);
                    s4[n][jj] = pv;
                    lsum[jj] += pv;
                }
#pragma unroll
            for (int off = 1; off < 16; off <<= 1)
#pragma unroll
                for (int jj = 0; jj < 4; ++jj)
                    lsum[jj] += __shfl_xor(lsum[jj], off);
#pragma unroll
            for (int jj = 0; jj < 4; ++jj)
                lrow[jj] = lrow[jj] * sc[jj] + lsum[jj];
#pragma unroll
            for (int nf = 0; nf < 16; ++nf)
#pragma unroll
                for (int jj = 0; jj < 4; ++jj)
                    o[nf][jj] *= sc[jj];

            // P -> LDS (bf16 A-frag layout), XOR-swizzled: elem ^= (row&7)<<3
#pragma unroll
            for (int n = 0; n < 4; ++n)
#pragma unroll
                for (int jj = 0; jj < 4; ++jj) {
                    int row16 = hi * 4 + jj;
                    int idx = (row16 * 64 + (n * 16 + lo)) ^ ((row16 & 7) << 3);
                    P[w][idx] = f2bf(s4[n][jj]);
                }

            __syncthreads();    // drains V(kt) staging (and K(kt+NSPLIT)); PV may read Vs

            __builtin_amdgcn_s_setprio(1);
#pragma unroll
            for (int k2 = 0; k2 < 2; ++k2) {
                short8 pa = *reinterpret_cast<const short8*>(
                    &P[w][(lo * 64 + k2 * 32 + hi * 8) ^ ((lo & 7) << 3)]);
#pragma unroll
                for (int nf = 0; nf < 16; ++nf) {
                    short8 vf = *reinterpret_cast<const short8*>(&Vs[((k2 * 16 + nf) * 64 + lane) * 8]);
                    o[nf] = mfma16(pa, vf, o[nf]);
                }
            }
            __builtin_amdgcn_s_setprio(0);
            __syncthreads();    // all Vs reads done before next iter restages it
            cur ^= 1;
        }

        size_t pb = (size_t)(b * 16 + j) * NSPLIT + p;
        short* POb = PO + pb * (256 * 256);
        float* PMLb = PML + pb * 512;
#pragma unroll
        for (int nf = 0; nf < 16; ++nf)
#pragma unroll
            for (int jj = 0; jj < 4; ++jj)
                POb[(w * 16 + hi * 4 + jj) * 256 + nf * 16 + lo] = f2bf(o[nf][jj]);
        if (lo == 0)
#pragma unroll
            for (int jj = 0; jj < 4; ++jj) {
                PMLb[w * 16 + hi * 4 + jj] = mrow[jj];
                PMLb[256 + w * 16 + hi * 4 + jj] = lrow[jj];
            }
    }
}

// ---- r17 512-thread attn (proven 73us) — fallback path ----
template <int NSPLIT, bool DIRECT>
__global__ __launch_bounds__(512) void attn_fwd(
    const short* __restrict__ Qf, const short* __restrict__ Kf,
    const short* __restrict__ Vf, short* __restrict__ PO,
    float* __restrict__ PML, short* __restrict__ Sc)
{
    __shared__ short Ks[2][64 * 256];   // 2 x 32 KB
    __shared__ short Vs[2][64 * 256];   // 2 x 32 KB
    __shared__ short P[8][16 * 64];     // 16 KB, XOR-swizzled

    const int tid = threadIdx.x;
    const int lane = tid & 63;
    const int w = tid >> 6;             // wave 0..7
    const int lo = lane & 15, hi = lane >> 4;
    const int bx = (int)blockIdx.x;
    const int m = bx / (BATCH * NSPLIT);        // pair id 0..15
    const int r = bx % (BATCH * NSPLIT);
    const int b = r % BATCH;
    const int p = r / BATCH;

    auto stage = [&](int buf, int kt) {
        const short* Kt = Kf + (size_t)(b * 64 + kt) * 16384;
        const short* Vt = Vf + (size_t)(b * 64 + kt) * 16384;
#pragma unroll
        for (int c4 = 0; c4 < 4; ++c4) {
            int c = c4 * 8 + w;
            gload16(Kt + c * 512 + lane * 8, &Ks[buf][c * 512]);
            gload16(Vt + c * 512 + lane * 8, &Vs[buf][c * 512]);
        }
    };

    for (int half = 0; half < 2; ++half) {
        const int j = half == 0 ? (31 - m) : m;
        const int q0 = j * 128;
        const int last = 2 * j + 1;

        short8 qv[8];
#pragma unroll
        for (int kk = 0; kk < 8; ++kk)
            qv[kk] = *reinterpret_cast<const short8*>(
                Qf + (((size_t)(b * 256 + j * 8 + w) * 8 + kk) * 64 + lane) * 8);

        f32x4 o[16] = {};
        float mrow[4] = {-1e30f, -1e30f, -1e30f, -1e30f};
        float lrow[4] = {0.f, 0.f, 0.f, 0.f};

        int cur = 0;
        if (p <= last) stage(0, p);
        __syncthreads();

        for (int kt = p; kt <= last; kt += NSPLIT) {
            if (kt + NSPLIT <= last) stage(cur ^ 1, kt + NSPLIT);

            f32x4 s4[4] = {};
            __builtin_amdgcn_s_setprio(1);
#pragma unroll
            for (int kk = 0; kk < 8; ++kk) {
#pragma unroll
                for (int n = 0; n < 4; ++n) {
                    short8 kf = *reinterpret_cast<const short8*>(&Ks[cur][((kk * 4 + n) * 64 + lane) * 8]);
                    s4[n] = mfma16(qv[kk], kf, s4[n]);
                }
            }
            __builtin_amdgcn_s_setprio(0);

            const bool diag = (kt >= 2 * j);
            float pm[4] = {-1e30f, -1e30f, -1e30f, -1e30f};
#pragma unroll
            for (int n = 0; n < 4; ++n) {
#pragma unroll
                for (int jj = 0; jj < 4; ++jj) {
                    float v = s4[n][jj] * 0.0625f;
                    if (diag) {
                        int rl = q0 + w * 16 + hi * 4 + jj;
                        int cl = kt * 64 + n * 16 + lo;
                        if (cl > rl) v = -1e30f;
                    }
                    s4[n][jj] = v;
                    pm[jj] = fmaxf(pm[jj], v);
                }
            }
#pragma unroll
            for (int off = 1; off < 16; off <<= 1)
#pragma unroll
                for (int jj = 0; jj < 4; ++jj)
                    pm[jj] = fmaxf(pm[jj], __shfl_xor(pm[jj], off));

            float sc[4], lsum[4];
#pragma unroll
            for (int jj = 0; jj < 4; ++jj) {
                float mn = fmaxf(mrow[jj], pm[jj]);
                sc[jj] = __expf(mrow[jj] - mn);
                mrow[jj] = mn;
                lsum[jj] = 0.f;
            }
#pragma unroll
            for (int n = 0; n < 4; ++n)
#pragma unroll
                for (int jj = 0; jj < 4; ++jj) {
                    float pv = __expf(s4[n][jj] - mrow[jj]);
                    s4[n][jj] = pv;
                    lsum[jj] += pv;
                }
#pragma unroll
            for (int off = 1; off < 16; off <<= 1)
#pragma unroll
                for (int jj = 0; jj < 4; ++jj)
                    lsum[jj] += __shfl_xor(lsum[jj], off);
#pragma unroll
            for (int jj = 0; jj < 4; ++jj)
                lrow[jj] = lrow[jj] * sc[jj] + lsum[jj];
#pragma unroll
            for (int nf = 0; nf < 16; ++nf)
#pragma unroll
                for (int jj = 0; jj < 4; ++jj)
                    o[nf][jj] *= sc[jj];

#pragma unroll
            for (int n = 0; n < 4; ++n)
#pragma unroll
                for (int jj = 0; jj < 4; ++jj) {
                    int row16 = hi * 4 + jj;
                    int idx = (row16 * 64 + (n * 16 + lo)) ^ ((row16 & 7) << 3);
                    P[w][idx] = f2bf(s4[n][jj]);
                }

            __builtin_amdgcn_s_setprio(1);
#pragma unroll
            for (int k2 = 0; k2 < 2; ++k2) {
                short8 pa = *reinterpret_cast<const short8*>(
                    &P[w][(lo * 64 + k2 * 32 + hi * 8) ^ ((lo & 7) << 3)]);
#pragma unroll
                for (int nf = 0; nf < 16; ++nf) {
                    short8 vf = *reinterpret_cast<const short8*>(&Vs[cur][((k2 * 16 + nf) * 64 + lane) * 8]);
                    o[nf] = mfma16(pa, vf, o[nf]);
                }
            }
            __builtin_amdgcn_s_setprio(0);
            __syncthreads();
            cur ^= 1;
        }

        if constexpr (DIRECT) {
            short* Sb = Sc + (size_t)b * S_LEN * D_DIM;
#pragma unroll
            for (int nf = 0; nf < 16; ++nf)
#pragma unroll
                for (int jj = 0; jj < 4; ++jj) {
                    size_t row = q0 + w * 16 + hi * 4 + jj;
                    Sb[row * D_DIM + nf * 16 + lo] = f2bf(o[nf][jj] / lrow[jj]);
                }
        } else {
            size_t pb = (size_t)(b * 32 + j) * NSPLIT + p;
            short* POb = PO + pb * (128 * 256);
            float* PMLb = PML + pb * 256;
#pragma unroll
            for (int nf = 0; nf < 16; ++nf)
#pragma unroll
                for (int jj = 0; jj < 4; ++jj)
                    POb[(w * 16 + hi * 4 + jj) * 256 + nf * 16 + lo] = f2bf(o[nf][jj]);
            if (lo == 0)
#pragma unroll
                for (int jj = 0; jj < 4; ++jj) {
                    PMLb[w * 16 + hi * 4 + jj] = mrow[jj];
                    PMLb[128 + w * 16 + hi * 4 + jj] = lrow[jj];
                }
        }
    }
}

extern "C" void kernel_launch(void* const* d_in, const int* in_sizes, int n_in,
                              void* d_out, int out_size, void* d_ws, size_t ws_size,
                              hipStream_t stream)
{
    const float* x  = (const float*)d_in[0];
    // d_in[1] = mask (int32 tril) — causality applied analytically, not read
    const float* wq = (const float*)d_in[2];
    const float* bq = (const float*)d_in[3];
    const float* wk = (const float*)d_in[4];
    const float* bk = (const float*)d_in[5];
    const float* wv = (const float*)d_in[6];
    const float* bv = (const float*)d_in[7];
    const float* wo = (const float*)d_in[8];
    const float* bo = (const float*)d_in[9];
    float* out = (float*)d_out;

    const size_t NTOK = (size_t)BATCH * S_LEN;          // 16384
    const size_t TD = NTOK * D_DIM;                     // 4,194,304
    short* WT = (short*)d_ws;                           // 4*65536 bf16
    short* QF = WT + 4 * 65536;
    short* KF = QF + TD;
    short* VF = KF + TD;
    short* xb = VF + TD;       // bf16 x; dead after gemm_qkv -> POs overlaps it
    short* POs = xb;           // bf16 partials (overlap, xb dead by then)
    short* Sw = QF;            // DIRECT-path S buffer (aliases QF)
    const size_t po_off_b = (size_t)(4 * 65536 + 3 * TD) * 2;  // 25,690,112
    const size_t xb_end_b = po_off_b + TD * 2;                 // 34,078,720

    // big path (NSPLIT=8, 256-row blocks): PO 512x131072B + PML 512x2048B
    const size_t big_need = po_off_b + (size_t)512 * 131072 + (size_t)512 * 2048;
    // r17 path (NSPLIT=4, 128-row blocks)
    const size_t part_b = TD * 2 + (size_t)128 * 256 * 4;
    const size_t r17_need = po_off_b + 4 * part_b;

    const int M = (int)NTOK;

    xbf_conv<<<dim3(2048), 256, 0, stream>>>(x, xb);
    transpose_w<<<dim3(16, 16, 4), dim3(16, 16), 0, stream>>>(wq, wk, wv, wo, WT);
    gemm_qkv<<<dim3(6, M / 128), 256, 0, stream>>>(xb, WT, bq, bk, bv, QF, KF, VF);

    if (ws_size >= big_need && ws_size >= xb_end_b) {
        float* PML = (float*)(POs + (size_t)512 * 65536);
        attn_big<8><<<dim3(8 * BATCH * 8), 1024, 0, stream>>>(QF, KF, VF, POs, PML);
        calc_sfac<8, 256><<<dim3(64), 256, 0, stream>>>(PML);
        gemm_out_fused<8, 256, 16><<<dim3(2, M / 128), 256, 0, stream>>>(POs, PML, WT + 3 * 65536, bo, out);
    } else if (ws_size >= r17_need && ws_size >= xb_end_b) {
        float* PML = (float*)(POs + 4 * TD);
        attn_fwd<4, false><<<dim3(16 * BATCH * 4), 512, 0, stream>>>(QF, KF, VF, POs, PML, Sw);
        calc_sfac<4, 128><<<dim3(128), 128, 0, stream>>>(PML);
        gemm_out_fused<4, 128, 32><<<dim3(2, M / 128), 256, 0, stream>>>(POs, PML, WT + 3 * 65536, bo, out);
    } else {
        attn_fwd<1, true><<<dim3(16 * BATCH), 512, 0, stream>>>(QF, KF, VF, nullptr, nullptr, Sw);
        gemm_out<<<dim3(2, M / 128), 256, 0, stream>>>(Sw, WT + 3 * 65536, bo, out, 256);
    }
}

// Round 22
// 119.944 us; speedup vs baseline: 1.8546x; 1.8546x over previous
//
#include <hip/hip_runtime.h>
#include <stdint.h>
#include <type_traits>

typedef __attribute__((ext_vector_type(8))) short short8;
typedef __attribute__((ext_vector_type(4))) short s16x4;
typedef __attribute__((ext_vector_type(4))) float f32x4;

#define S_LEN 4096
#define D_DIM 256
#define BATCH 4

__device__ __forceinline__ f32x4 mfma16(short8 a, short8 b, f32x4 c) {
    return __builtin_amdgcn_mfma_f32_16x16x32_bf16(a, b, c, 0, 0, 0);
}

// fp32 -> bf16 bits, round-to-nearest-even (matches numpy/ml_dtypes)
__device__ __forceinline__ short f2bf(float x) {
    uint32_t u = __float_as_uint(x);
    uint32_t r = (u + 0x7FFFu + ((u >> 16) & 1u)) >> 16;
    return (short)r;
}
__device__ __forceinline__ float bf2f(short s) {
    uint32_t u = ((uint32_t)(uint16_t)s) << 16;
    return __uint_as_float(u);
}

// async global->LDS, 16B per lane. LDS dest wave-uniform base; HW adds lane*16.
__device__ __forceinline__ void gload16(const short* g, short* l) {
    __builtin_amdgcn_global_load_lds(
        (const __attribute__((address_space(1))) void*)g,
        (__attribute__((address_space(3))) void*)l, 16, 0, 0);
}

// ---- x fp32 -> bf16 (xb read 6x by gemm_qkv from L2/L3 instead of fp32 6x) ----
__global__ __launch_bounds__(256) void xbf_conv(
    const float* __restrict__ x, short* __restrict__ xb)
{
    int i = blockIdx.x * 256 + threadIdx.x;   // 8 elems per thread
    f32x4 a = *reinterpret_cast<const f32x4*>(x + (size_t)i * 8);
    f32x4 b = *reinterpret_cast<const f32x4*>(x + (size_t)i * 8 + 4);
    short8 r;
#pragma unroll
    for (int k = 0; k < 4; ++k) r[k] = f2bf(a[k]);
#pragma unroll
    for (int k = 0; k < 4; ++k) r[k + 4] = f2bf(b[k]);
    *reinterpret_cast<short8*>(xb + (size_t)i * 8) = r;
}

// ---- transpose four 256x256 fp32 weights into bf16 ws (WT[z][f][d] = W[z][d][f]) ----
__global__ __launch_bounds__(256) void transpose_w(
    const float* __restrict__ wq, const float* __restrict__ wk,
    const float* __restrict__ wv, const float* __restrict__ wo,
    short* __restrict__ out)
{
    __shared__ float t[16][17];
    const float* in = blockIdx.z == 0 ? wq : blockIdx.z == 1 ? wk
                    : blockIdx.z == 2 ? wv : wo;
    short* o = out + (size_t)blockIdx.z * 65536;
    const int x0 = blockIdx.x * 16, y0 = blockIdx.y * 16;
    const int tx = threadIdx.x, ty = threadIdx.y;
    t[ty][tx] = in[(y0 + ty) * 256 + x0 + tx];
    __syncthreads();
    o[(size_t)(x0 + ty) * 256 + y0 + tx] = f2bf(t[tx][ty]);
}

// ---- fused QKV GEMM: [16384 x 768] = xb(bf16)[16384x256] * WT[768x256]^T + bias ----
__global__ __launch_bounds__(256) void gemm_qkv(
    const short* __restrict__ A, const short* __restrict__ Bt,
    const float* __restrict__ bq, const float* __restrict__ bk,
    const float* __restrict__ bv,
    short* __restrict__ QF, short* __restrict__ KF, short* __restrict__ VF)
{
    __shared__ short As[128 * 64];
    __shared__ short Bs[128 * 64];
    const int tid = threadIdx.x;
    const int lane = tid & 63;
    const int w = tid >> 6;
    const int wr = w >> 1, wc = w & 1;
    const int lo = lane & 15, hi = lane >> 4;
    const size_t m0 = (size_t)blockIdx.y * 128, n0 = (size_t)blockIdx.x * 128;
    const int reg = (int)(n0 >> 8);                  // 0=Q 1=K 2=V (block-uniform)
    const float* bias = reg == 0 ? bq : (reg == 1 ? bk : bv);

    f32x4 acc[4][4] = {};

    for (int kt = 0; kt < 4; ++kt) {
#pragma unroll
        for (int i = 0; i < 4; ++i) {
            int c = i * 4 + w;                     // chunk 0..15
            int s = c * 64 + lane;                 // 16B slot 0..1023
            int row = s >> 3, ke = (s & 7) * 8;
            gload16(A  + (m0 + row) * 256 + kt * 64 + ke, As + c * 512);
            gload16(Bt + (n0 + row) * 256 + kt * 64 + ke, Bs + c * 512);
        }
        __syncthreads();
#pragma unroll
        for (int kk = 0; kk < 2; ++kk) {
            short8 af[4], bf[4];
#pragma unroll
            for (int m = 0; m < 4; ++m)
                af[m] = *reinterpret_cast<const short8*>(&As[(wr * 64 + m * 16 + lo) * 64 + kk * 32 + hi * 8]);
#pragma unroll
            for (int n = 0; n < 4; ++n)
                bf[n] = *reinterpret_cast<const short8*>(&Bs[(wc * 64 + n * 16 + lo) * 64 + kk * 32 + hi * 8]);
#pragma unroll
            for (int m = 0; m < 4; ++m)
#pragma unroll
                for (int n = 0; n < 4; ++n)
                    acc[m][n] = mfma16(af[m], bf[n], acc[m][n]);
        }
        __syncthreads();
    }

#pragma unroll
    for (int m = 0; m < 4; ++m) {
#pragma unroll
        for (int n = 0; n < 4; ++n) {
#pragma unroll
            for (int j = 0; j < 4; ++j) {
                size_t row = m0 + wr * 64 + m * 16 + hi * 4 + j;
                int f = (int)((n0 + wc * 64 + n * 16 + lo) & 255);
                float v = acc[m][n][j] + bias[f];
                int b = (int)(row >> 12), R = (int)(row & 4095);
                if (reg == 0) {
                    int jt = R >> 4, lk = R & 15;
                    int kk = f >> 5, q = f & 31, hk = q >> 3, e = q & 7;
                    QF[((((size_t)(b * 256 + jt) * 8 + kk) * 64) + hk * 16 + lk) * 8 + e] = f2bf(v);
                } else if (reg == 1) {
                    int ktile = R >> 6, nn = (R >> 4) & 3, lk = R & 15;
                    int kk = f >> 5, q = f & 31, hk = q >> 3, e = q & 7;
                    KF[(((((size_t)(b * 64 + ktile) * 8 + kk) * 4 + nn) * 64) + hk * 16 + lk) * 8 + e] = f2bf(v);
                } else {
                    int ktile = R >> 6, t6 = R & 63, k2 = t6 >> 5, r5 = t6 & 31;
                    int hk = r5 >> 3, e = r5 & 7;
                    int nf = f >> 4, lk = f & 15;
                    VF[(((((size_t)(b * 64 + ktile) * 2 + k2) * 16 + nf) * 64) + hk * 16 + lk) * 8 + e] = f2bf(v);
                }
            }
        }
    }
}

// ---- out-proj GEMM (plain): C = S*WoT^T + bias (DIRECT fallback path) ----
__global__ __launch_bounds__(256) void gemm_out(
    const short* __restrict__ A, const short* __restrict__ Bt,
    const float* __restrict__ bias, float* __restrict__ C, int ldc)
{
    __shared__ short As[128 * 64];
    __shared__ short Bs[128 * 64];
    const int tid = threadIdx.x;
    const int lane = tid & 63;
    const int w = tid >> 6;
    const int wr = w >> 1, wc = w & 1;
    const int lo = lane & 15, hi = lane >> 4;
    const size_t m0 = (size_t)blockIdx.y * 128, n0 = (size_t)blockIdx.x * 128;

    f32x4 acc[4][4] = {};

    for (int kt = 0; kt < 4; ++kt) {
#pragma unroll
        for (int i = 0; i < 4; ++i) {
            int c = i * 4 + w;
            int s = c * 64 + lane;
            int row = s >> 3, ke = (s & 7) * 8;
            gload16(A  + (m0 + row) * 256 + kt * 64 + ke, As + c * 512);
            gload16(Bt + (n0 + row) * 256 + kt * 64 + ke, Bs + c * 512);
        }
        __syncthreads();
#pragma unroll
        for (int kk = 0; kk < 2; ++kk) {
            short8 af[4], bf[4];
#pragma unroll
            for (int m = 0; m < 4; ++m)
                af[m] = *reinterpret_cast<const short8*>(&As[(wr * 64 + m * 16 + lo) * 64 + kk * 32 + hi * 8]);
#pragma unroll
            for (int n = 0; n < 4; ++n)
                bf[n] = *reinterpret_cast<const short8*>(&Bs[(wc * 64 + n * 16 + lo) * 64 + kk * 32 + hi * 8]);
#pragma unroll
            for (int m = 0; m < 4; ++m)
#pragma unroll
                for (int n = 0; n < 4; ++n)
                    acc[m][n] = mfma16(af[m], bf[n], acc[m][n]);
        }
        __syncthreads();
    }

#pragma unroll
    for (int m = 0; m < 4; ++m)
#pragma unroll
        for (int n = 0; n < 4; ++n)
#pragma unroll
            for (int j = 0; j < 4; ++j) {
                size_t row = m0 + wr * 64 + m * 16 + hi * 4 + j;
                size_t col = n0 + wc * 64 + n * 16 + lo;
                C[row * (size_t)ldc + col] = acc[m][n][j] + bias[col];
            }
}

// ---- PML (m,l) -> in-place per-row scale factors e_p/L ----
template <int NSPLIT>
__global__ __launch_bounds__(128) void calc_sfac(float* __restrict__ PML)
{
    const int bid = (int)blockIdx.x;        // b*32 + j, 0..127
    const int lr = threadIdx.x;             // local row 0..127
    const size_t base = (size_t)bid * NSPLIT;

    float mm[NSPLIT], ll[NSPLIT];
    float M = -3.3e38f;
#pragma unroll
    for (int p = 0; p < NSPLIT; ++p) {
        mm[p] = PML[(base + p) * 256 + lr];
        ll[p] = PML[(base + p) * 256 + 128 + lr];
        M = fmaxf(M, mm[p]);
    }
    float L = 0.f, e[NSPLIT];
#pragma unroll
    for (int p = 0; p < NSPLIT; ++p) { e[p] = __expf(mm[p] - M); L += ll[p] * e[p]; }
    const float inv = 1.0f / L;
#pragma unroll
    for (int p = 0; p < NSPLIT; ++p)
        PML[(base + p) * 256 + lr] = e[p] * inv;
}

// ---- fused merge + out-proj: out = (Σ_p sf_p ⊙ PO_p) * WoT^T + bias ----
// A-operand merged in registers during staging; B async-staged.
template <int NSPLIT>
__global__ __launch_bounds__(256) void gemm_out_fused(
    const short* __restrict__ PO, const float* __restrict__ PML,
    const short* __restrict__ Bt, const float* __restrict__ bias,
    float* __restrict__ C)
{
    __shared__ short As[128 * 64];
    __shared__ short Bs[128 * 64];
    const int tid = threadIdx.x;
    const int lane = tid & 63;
    const int w = tid >> 6;
    const int wr = w >> 1, wc = w & 1;
    const int lo = lane & 15, hi = lane >> 4;
    const size_t m0 = (size_t)blockIdx.y * 128, n0 = (size_t)blockIdx.x * 128;

    f32x4 acc[4][4] = {};

    for (int kt = 0; kt < 4; ++kt) {
        short8 va[4];
#pragma unroll
        for (int i = 0; i < 4; ++i) {
            int c = i * 4 + w;                     // chunk 0..15
            int s = c * 64 + lane;                 // 16B slot 0..1023
            int row = s >> 3, ke = (s & 7) * 8;
            size_t grow = m0 + row;
            int b = (int)(grow >> 12), R = (int)(grow & 4095);
            int jq = R >> 7, lr = R & 127;
            size_t pb0 = (size_t)(b * 32 + jq) * NSPLIT;

            float a8[8] = {};
#pragma unroll
            for (int p = 0; p < NSPLIT; ++p) {
                float sf = PML[(pb0 + p) * 256 + lr];
                short8 v = *reinterpret_cast<const short8*>(
                    &PO[(pb0 + p) * 32768 + (size_t)lr * 256 + kt * 64 + ke]);
#pragma unroll
                for (int ii = 0; ii < 8; ++ii) a8[ii] += bf2f(v[ii]) * sf;
            }
#pragma unroll
            for (int ii = 0; ii < 8; ++ii) va[i][ii] = f2bf(a8[ii]);

            gload16(Bt + (n0 + row) * 256 + kt * 64 + ke, Bs + c * 512);
        }
#pragma unroll
        for (int i = 0; i < 4; ++i) {
            int c = i * 4 + w;
            *reinterpret_cast<short8*>(&As[(c * 64 + lane) * 8]) = va[i];
        }
        __syncthreads();
#pragma unroll
        for (int kk = 0; kk < 2; ++kk) {
            short8 af[4], bf[4];
#pragma unroll
            for (int m = 0; m < 4; ++m)
                af[m] = *reinterpret_cast<const short8*>(&As[(wr * 64 + m * 16 + lo) * 64 + kk * 32 + hi * 8]);
#pragma unroll
            for (int n = 0; n < 4; ++n)
                bf[n] = *reinterpret_cast<const short8*>(&Bs[(wc * 64 + n * 16 + lo) * 64 + kk * 32 + hi * 8]);
#pragma unroll
            for (int m = 0; m < 4; ++m)
#pragma unroll
                for (int n = 0; n < 4; ++n)
                    acc[m][n] = mfma16(af[m], bf[n], acc[m][n]);
        }
        __syncthreads();
    }

#pragma unroll
    for (int m = 0; m < 4; ++m)
#pragma unroll
        for (int n = 0; n < 4; ++n)
#pragma unroll
            for (int j = 0; j < 4; ++j) {
                size_t row = m0 + wr * 64 + m * 16 + hi * 4 + j;
                size_t col = n0 + wc * 64 + n * 16 + lo;
                C[row * (size_t)256 + col] = acc[m][n][j] + bias[col];
            }
}

// ---- causal flash attention: 512-thread blocks (8 waves = 2/SIMD guaranteed) ----
// Measured-best structure (73us, 112 VGPR, no spill, 0 bank conflicts):
// K+V double-buffered in LDS shared by 8 waves; mirror pairs (j=31-m then m)
// + parity split-K; P XOR-swizzled.
template <int NSPLIT, bool DIRECT>
__global__ __launch_bounds__(512) void attn_fwd(
    const short* __restrict__ Qf, const short* __restrict__ Kf,
    const short* __restrict__ Vf, short* __restrict__ PO,
    float* __restrict__ PML, short* __restrict__ Sc)
{
    __shared__ short Ks[2][64 * 256];   // 2 x 32 KB
    __shared__ short Vs[2][64 * 256];   // 2 x 32 KB
    __shared__ short P[8][16 * 64];     // 16 KB, XOR-swizzled

    const int tid = threadIdx.x;
    const int lane = tid & 63;
    const int w = tid >> 6;             // wave 0..7
    const int lo = lane & 15, hi = lane >> 4;
    const int bx = (int)blockIdx.x;
    const int m = bx / (BATCH * NSPLIT);        // pair id 0..15
    const int r = bx % (BATCH * NSPLIT);
    const int b = r % BATCH;                    // bx%8 -> batch pinned to XCD pair
    const int p = r / BATCH;

    auto stage = [&](int buf, int kt) {
        const short* Kt = Kf + (size_t)(b * 64 + kt) * 16384;
        const short* Vt = Vf + (size_t)(b * 64 + kt) * 16384;
#pragma unroll
        for (int c4 = 0; c4 < 4; ++c4) {
            int c = c4 * 8 + w;                 // 1KB chunk per call, 8 waves
            gload16(Kt + c * 512 + lane * 8, &Ks[buf][c * 512]);
            gload16(Vt + c * 512 + lane * 8, &Vs[buf][c * 512]);
        }
    };

    for (int half = 0; half < 2; ++half) {
        const int j = half == 0 ? (31 - m) : m;   // 128-row q-block, long first
        const int q0 = j * 128;
        const int last = 2 * j + 1;               // last 64-key k-tile index

        short8 qv[8];
#pragma unroll
        for (int kk = 0; kk < 8; ++kk)
            qv[kk] = *reinterpret_cast<const short8*>(
                Qf + (((size_t)(b * 256 + j * 8 + w) * 8 + kk) * 64 + lane) * 8);

        f32x4 o[16] = {};
        float mrow[4] = {-1e30f, -1e30f, -1e30f, -1e30f};
        float lrow[4] = {0.f, 0.f, 0.f, 0.f};

        int cur = 0;
        if (p <= last) stage(0, p);
        __syncthreads();                          // first tile staged

        for (int kt = p; kt <= last; kt += NSPLIT) {
            if (kt + NSPLIT <= last) stage(cur ^ 1, kt + NSPLIT);   // prefetch next

            f32x4 s4[4] = {};
            __builtin_amdgcn_s_setprio(1);
#pragma unroll
            for (int kk = 0; kk < 8; ++kk) {
#pragma unroll
                for (int n = 0; n < 4; ++n) {
                    short8 kf = *reinterpret_cast<const short8*>(&Ks[cur][((kk * 4 + n) * 64 + lane) * 8]);
                    s4[n] = mfma16(qv[kk], kf, s4[n]);
                }
            }
            __builtin_amdgcn_s_setprio(0);

            const bool diag = (kt >= 2 * j);
            float pm[4] = {-1e30f, -1e30f, -1e30f, -1e30f};
#pragma unroll
            for (int n = 0; n < 4; ++n) {
#pragma unroll
                for (int jj = 0; jj < 4; ++jj) {
                    float v = s4[n][jj] * 0.0625f;  // 1/sqrt(256)
                    if (diag) {
                        int rl = q0 + w * 16 + hi * 4 + jj;
                        int cl = kt * 64 + n * 16 + lo;
                        if (cl > rl) v = -1e30f;    // causal mask
                    }
                    s4[n][jj] = v;
                    pm[jj] = fmaxf(pm[jj], v);
                }
            }
#pragma unroll
            for (int off = 1; off < 16; off <<= 1)
#pragma unroll
                for (int jj = 0; jj < 4; ++jj)
                    pm[jj] = fmaxf(pm[jj], __shfl_xor(pm[jj], off));

            float sc[4], lsum[4];
#pragma unroll
            for (int jj = 0; jj < 4; ++jj) {
                float mn = fmaxf(mrow[jj], pm[jj]);
                sc[jj] = __expf(mrow[jj] - mn);
                mrow[jj] = mn;
                lsum[jj] = 0.f;
            }
#pragma unroll
            for (int n = 0; n < 4; ++n)
#pragma unroll
                for (int jj = 0; jj < 4; ++jj) {
                    float pv = __expf(s4[n][jj] - mrow[jj]);
                    s4[n][jj] = pv;
                    lsum[jj] += pv;
                }
#pragma unroll
            for (int off = 1; off < 16; off <<= 1)
#pragma unroll
                for (int jj = 0; jj < 4; ++jj)
                    lsum[jj] += __shfl_xor(lsum[jj], off);
#pragma unroll
            for (int jj = 0; jj < 4; ++jj)
                lrow[jj] = lrow[jj] * sc[jj] + lsum[jj];
#pragma unroll
            for (int nf = 0; nf < 16; ++nf)
#pragma unroll
                for (int jj = 0; jj < 4; ++jj)
                    o[nf][jj] *= sc[jj];

            // P -> LDS (bf16 A-frag layout), XOR-swizzled: elem ^= (row&7)<<3
#pragma unroll
            for (int n = 0; n < 4; ++n)
#pragma unroll
                for (int jj = 0; jj < 4; ++jj) {
                    int row16 = hi * 4 + jj;
                    int idx = (row16 * 64 + (n * 16 + lo)) ^ ((row16 & 7) << 3);
                    P[w][idx] = f2bf(s4[n][jj]);
                }

            __builtin_amdgcn_s_setprio(1);
#pragma unroll
            for (int k2 = 0; k2 < 2; ++k2) {
                short8 pa = *reinterpret_cast<const short8*>(
                    &P[w][(lo * 64 + k2 * 32 + hi * 8) ^ ((lo & 7) << 3)]);
#pragma unroll
                for (int nf = 0; nf < 16; ++nf) {
                    short8 vf = *reinterpret_cast<const short8*>(&Vs[cur][((k2 * 16 + nf) * 64 + lane) * 8]);
                    o[nf] = mfma16(pa, vf, o[nf]);
                }
            }
            __builtin_amdgcn_s_setprio(0);
            __syncthreads();    // drains prefetch (vmcnt0) + protects buffers/P
            cur ^= 1;
        }

        if constexpr (DIRECT) {
            short* Sb = Sc + (size_t)b * S_LEN * D_DIM;
#pragma unroll
            for (int nf = 0; nf < 16; ++nf)
#pragma unroll
                for (int jj = 0; jj < 4; ++jj) {
                    size_t row = q0 + w * 16 + hi * 4 + jj;
                    Sb[row * D_DIM + nf * 16 + lo] = f2bf(o[nf][jj] / lrow[jj]);
                }
        } else {
            size_t pb = (size_t)(b * 32 + j) * NSPLIT + p;
            short* POb = PO + pb * (128 * 256);
            float* PMLb = PML + pb * 256;
#pragma unroll
            for (int nf = 0; nf < 16; ++nf)
#pragma unroll
                for (int jj = 0; jj < 4; ++jj)
                    POb[(w * 16 + hi * 4 + jj) * 256 + nf * 16 + lo] = f2bf(o[nf][jj]);
            if (lo == 0)
#pragma unroll
                for (int jj = 0; jj < 4; ++jj) {
                    PMLb[w * 16 + hi * 4 + jj] = mrow[jj];
                    PMLb[128 + w * 16 + hi * 4 + jj] = lrow[jj];
                }
        }
    }
}

extern "C" void kernel_launch(void* const* d_in, const int* in_sizes, int n_in,
                              void* d_out, int out_size, void* d_ws, size_t ws_size,
                              hipStream_t stream)
{
    const float* x  = (const float*)d_in[0];
    // d_in[1] = mask (int32 tril) — causality applied analytically, not read
    const float* wq = (const float*)d_in[2];
    const float* bq = (const float*)d_in[3];
    const float* wk = (const float*)d_in[4];
    const float* bk = (const float*)d_in[5];
    const float* wv = (const float*)d_in[6];
    const float* bv = (const float*)d_in[7];
    const float* wo = (const float*)d_in[8];
    const float* bo = (const float*)d_in[9];
    float* out = (float*)d_out;

    const size_t NTOK = (size_t)BATCH * S_LEN;          // 16384
    const size_t TD = NTOK * D_DIM;                     // 4,194,304
    short* WT = (short*)d_ws;                           // 4*65536 bf16
    short* QF = WT + 4 * 65536;
    short* KF = QF + TD;
    short* VF = KF + TD;
    short* xb = VF + TD;       // bf16 x; dead after gemm_qkv -> POs overlaps it
    short* POs = xb;           // bf16 partials (overlap, xb dead by then)
    short* Sw = QF;            // DIRECT-path S buffer (aliases QF)
    const size_t po_off_b = (size_t)(4 * 65536 + 3 * TD) * 2;  // 25,690,112
    // per split: PO = TD bf16 (8.4MB) + PML = 128*256 fp32 (131KB)
    const size_t part_b = TD * 2 + (size_t)128 * 256 * 4;
    const size_t xb_end_b = po_off_b + TD * 2;                 // xb alone needs this

    const int M = (int)NTOK;

    xbf_conv<<<dim3(2048), 256, 0, stream>>>(x, xb);
    transpose_w<<<dim3(16, 16, 4), dim3(16, 16), 0, stream>>>(wq, wk, wv, wo, WT);
    gemm_qkv<<<dim3(6, M / 128), 256, 0, stream>>>(xb, WT, bq, bk, bv, QF, KF, VF);

    if (ws_size >= po_off_b + 4 * part_b && ws_size >= xb_end_b) {
        float* PML = (float*)(POs + 4 * TD);
        attn_fwd<4, false><<<dim3(16 * BATCH * 4), 512, 0, stream>>>(QF, KF, VF, POs, PML, Sw);
        calc_sfac<4><<<dim3(128), 128, 0, stream>>>(PML);
        gemm_out_fused<4><<<dim3(2, M / 128), 256, 0, stream>>>(POs, PML, WT + 3 * 65536, bo, out);
    } else if (ws_size >= po_off_b + 2 * part_b && ws_size >= xb_end_b) {
        float* PML = (float*)(POs + 2 * TD);
        attn_fwd<2, false><<<dim3(16 * BATCH * 2), 512, 0, stream>>>(QF, KF, VF, POs, PML, Sw);
        calc_sfac<2><<<dim3(128), 128, 0, stream>>>(PML);
        gemm_out_fused<2><<<dim3(2, M / 128), 256, 0, stream>>>(POs, PML, WT + 3 * 65536, bo, out);
    } else {
        attn_fwd<1, true><<<dim3(16 * BATCH), 512, 0, stream>>>(QF, KF, VF, nullptr, nullptr, Sw);
        gemm_out<<<dim3(2, M / 128), 256, 0, stream>>>(Sw, WT + 3 * 65536, bo, out, 256);
    }
}